// Round 5
// baseline (386.644 us; speedup 1.0000x reference)
//
#include <hip/hip_runtime.h>
#include <math.h>

#define B 64
#define T 2048
#define DS 512
#define DH 512
#define DA 512

typedef float fx4 __attribute__((ext_vector_type(4)));  // native vec: nt-load OK
typedef float fx2 __attribute__((ext_vector_type(2)));

// Fused kernel A+B: per block (b, q): compute phi_part[a] = s[b]·phi_w[a]+phi_b[a]
// for the q-th quarter of a (128 values) into LDS, then
// vp[q][b][k] = sum_{a in quarter} phi_part[a] * psi_w[a,k].
// 256 blocks keeps the 4-way a-split parallelism; all weight reads are L2-hot
// (phi_w/psi_w are 1 MB each). Saves a launch + the phi_s round-trip.
__global__ __launch_bounds__(256) void k_phiv(const float* __restrict__ s,
                                              const float* __restrict__ phi_w,
                                              const float* __restrict__ phi_b,
                                              const float* __restrict__ psi_w,
                                              float* __restrict__ vp) {
    __shared__ float phi_part[DA / 4];
    const int b = blockIdx.x >> 2;
    const int q = blockIdx.x & 3;
    const int tid  = threadIdx.x;
    const int wave = tid >> 6;
    const int lane = tid & 63;

    // s[b] fragment: 8 floats/lane, reused across all 32 dots of this wave
    const fx4* s4 = (const fx4*)(s + (size_t)b * DS);
    const fx4 sA = s4[lane * 2], sB = s4[lane * 2 + 1];

    // wave w computes a_local in [w*32, (w+1)*32)
    for (int i = 0; i < 32; ++i) {
        const int a_local = wave * 32 + i;
        const int a = q * (DA / 4) + a_local;
        const fx4* w4 = (const fx4*)(phi_w + (size_t)a * DS);
        const fx4 wA = w4[lane * 2], wB = w4[lane * 2 + 1];
        float acc = sA.x * wA.x + sA.y * wA.y + sA.z * wA.z + sA.w * wA.w
                  + sB.x * wB.x + sB.y * wB.y + sB.z * wB.z + sB.w * wB.w;
        #pragma unroll
        for (int off = 32; off > 0; off >>= 1)
            acc += __shfl_down(acc, off, 64);
        if (lane == 0) phi_part[a_local] = acc + phi_b[a];
    }
    __syncthreads();

    // vp partial GEMV: 256 threads x fx2 over k (DH/2 = 256 slots)
    const fx2* w2 = (const fx2*)psi_w;   // [a][DH/2]
    fx2 acc = {0.f, 0.f};
    #pragma unroll 8
    for (int a = 0; a < DA / 4; ++a) {
        const float p = phi_part[a];           // LDS broadcast, conflict-free
        acc += p * w2[(size_t)(q * (DA / 4) + a) * (DH / 2) + tid];
    }
    ((fx2*)(vp + ((size_t)q * B + b) * DH))[tid] = acc;
}

// Kernel C (the HBM-bound pass): e[b,t] = v[b] . h[b,t];  rs[b,t] = sum_k h[b,t,k]
// 16 rows per block (all same b): q-summed v[b] staged in LDS once per block,
// each wave keeps its v fragment in registers and streams 4 rows of h with
// batched non-temporal loads (8 dwordx4 in flight).
__global__ __launch_bounds__(256) void k_scores(const float* __restrict__ h,
                                                const float* __restrict__ vp,
                                                float* __restrict__ e,
                                                float* __restrict__ rs) {
    __shared__ float vsum[DH];
    const int tid  = threadIdx.x;
    const int base = blockIdx.x * 16;          // row base; 16 | T so same b
    const int b    = base >> 11;               // /T

    // stage q-summed v[b]: 256 threads x 2 floats, 8 KB of L2 reads per block
    {
        fx2 acc = {0.f, 0.f};
        #pragma unroll
        for (int q = 0; q < 4; ++q) {
            const fx2* v2 = (const fx2*)(vp + ((size_t)q * B + b) * DH);
            acc += v2[tid];
        }
        ((fx2*)vsum)[tid] = acc;
    }
    __syncthreads();

    const int wave = tid >> 6;
    const int lane = tid & 63;
    const fx4 vA = ((const fx4*)vsum)[lane * 2];
    const fx4 vB = ((const fx4*)vsum)[lane * 2 + 1];

    const int row0 = base + wave * 4;
    fx4 hA[4], hB[4];
    #pragma unroll
    for (int r = 0; r < 4; ++r) {
        const fx4* h4 = (const fx4*)(h + (size_t)(row0 + r) * DH);
        hA[r] = __builtin_nontemporal_load(&h4[lane * 2]);
        hB[r] = __builtin_nontemporal_load(&h4[lane * 2 + 1]);
    }

    float dot[4], sum[4];
    #pragma unroll
    for (int r = 0; r < 4; ++r) {
        dot[r] = hA[r].x * vA.x + hA[r].y * vA.y + hA[r].z * vA.z + hA[r].w * vA.w
               + hB[r].x * vB.x + hB[r].y * vB.y + hB[r].z * vB.z + hB[r].w * vB.w;
        sum[r] = hA[r].x + hA[r].y + hA[r].z + hA[r].w
               + hB[r].x + hB[r].y + hB[r].z + hB[r].w;
    }
    #pragma unroll
    for (int off = 32; off > 0; off >>= 1) {
        #pragma unroll
        for (int r = 0; r < 4; ++r) {
            dot[r] += __shfl_down(dot[r], off, 64);
            sum[r] += __shfl_down(sum[r], off, 64);
        }
    }
    if (lane == 0) {
        #pragma unroll
        for (int r = 0; r < 4; ++r) { e[row0 + r] = dot[r]; rs[row0 + r] = sum[r]; }
    }
}

// Kernel D: per-b softmax over t, fused with rowsum multiply.
// Shuffle-based reductions: 2 __syncthreads total (vs 16 tree rounds).
__global__ __launch_bounds__(256) void k_softmax(const float* __restrict__ e,
                                                 const float* __restrict__ rs,
                                                 float* __restrict__ c) {
    __shared__ float wred[4];
    const int b = blockIdx.x;
    const int tid  = threadIdx.x;
    const int wave = tid >> 6;
    const int lane = tid & 63;
    const fx4* eb = (const fx4*)(e + (size_t)b * T);

    fx4 evA = eb[tid * 2], evB = eb[tid * 2 + 1];

    float m = fmaxf(fmaxf(fmaxf(evA.x, evA.y), fmaxf(evA.z, evA.w)),
                    fmaxf(fmaxf(evB.x, evB.y), fmaxf(evB.z, evB.w)));
    #pragma unroll
    for (int off = 32; off > 0; off >>= 1)
        m = fmaxf(m, __shfl_down(m, off, 64));
    if (lane == 0) wred[wave] = m;
    __syncthreads();
    m = fmaxf(fmaxf(wred[0], wred[1]), fmaxf(wred[2], wred[3]));

    evA.x = expf(evA.x - m); evA.y = expf(evA.y - m);
    evA.z = expf(evA.z - m); evA.w = expf(evA.w - m);
    evB.x = expf(evB.x - m); evB.y = expf(evB.y - m);
    evB.z = expf(evB.z - m); evB.w = expf(evB.w - m);
    float lsum = evA.x + evA.y + evA.z + evA.w + evB.x + evB.y + evB.z + evB.w;
    #pragma unroll
    for (int off = 32; off > 0; off >>= 1)
        lsum += __shfl_down(lsum, off, 64);
    __syncthreads();              // protect wred reuse
    if (lane == 0) wred[wave] = lsum;
    __syncthreads();
    const float inv = 1.0f / (wred[0] + wred[1] + wred[2] + wred[3]);

    const fx4* rb = (const fx4*)(rs + (size_t)b * T);
    fx4* cb = (fx4*)(c + (size_t)b * T);
    fx4 rA = rb[tid * 2], rB = rb[tid * 2 + 1];
    fx4 oA, oB;
    oA.x = evA.x * inv * rA.x; oA.y = evA.y * inv * rA.y;
    oA.z = evA.z * inv * rA.z; oA.w = evA.w * inv * rA.w;
    oB.x = evB.x * inv * rB.x; oB.y = evB.y * inv * rB.y;
    oB.z = evB.z * inv * rB.z; oB.w = evB.w * inv * rB.w;
    cb[tid * 2] = oA;
    cb[tid * 2 + 1] = oB;
}

extern "C" void kernel_launch(void* const* d_in, const int* in_sizes, int n_in,
                              void* d_out, int out_size, void* d_ws, size_t ws_size,
                              hipStream_t stream) {
    const float* s     = (const float*)d_in[0];
    const float* h     = (const float*)d_in[1];
    const float* phi_w = (const float*)d_in[2];
    const float* phi_b = (const float*)d_in[3];
    const float* psi_w = (const float*)d_in[4];
    // d_in[5] = psi_b: adds a per-b constant to e[b,:] -> cancels in softmax.
    (void)in_sizes; (void)n_in; (void)out_size; (void)ws_size;

    float* out = (float*)d_out;
    float* ws  = (float*)d_ws;
    float* vp    = ws;                    // 4*B*DH   floats (512 KB)
    float* e     = vp + 4 * B * DH;       // B*T      floats (512 KB)
    float* rs    = e + B * T;             // B*T      floats (512 KB)

    k_phiv   <<<B * 4,      256, 0, stream>>>(s, phi_w, phi_b, psi_w, vp);
    k_scores <<<B * T / 16, 256, 0, stream>>>(h, vp, e, rs);
    k_softmax<<<B,          256, 0, stream>>>(e, rs, out);
}

// Round 6
// 373.769 us; speedup vs baseline: 1.0344x; 1.0344x over previous
//
#include <hip/hip_runtime.h>
#include <math.h>

#define B 64
#define T 2048
#define DS 512
#define DH 512
#define DA 512

typedef float fx4 __attribute__((ext_vector_type(4)));  // native vec: nt-load OK
typedef float fx2 __attribute__((ext_vector_type(2)));

// Kernel A: phi_s[b,a] = dot(s[b,:], phi_w[a,:]) + phi_b[a]
// One wave per output element (8192 independent waves -> latency fully hidden).
__global__ __launch_bounds__(256) void k_phi(const float* __restrict__ s,
                                             const float* __restrict__ phi_w,
                                             const float* __restrict__ phi_b,
                                             float* __restrict__ phi_s) {
    const int wave = threadIdx.x >> 6;
    const int lane = threadIdx.x & 63;
    const int out  = blockIdx.x * 4 + wave;   // [0, B*DA)
    const int b = out >> 9;                    // /512
    const int a = out & 511;

    const fx4* s4 = (const fx4*)(s + (size_t)b * DS);
    const fx4* w4 = (const fx4*)(phi_w + (size_t)a * DS);
    fx4 sA = s4[lane * 2], sB = s4[lane * 2 + 1];
    fx4 wA = w4[lane * 2], wB = w4[lane * 2 + 1];
    float acc = sA.x * wA.x + sA.y * wA.y + sA.z * wA.z + sA.w * wA.w
              + sB.x * wB.x + sB.y * wB.y + sB.z * wB.z + sB.w * wB.w;
    #pragma unroll
    for (int off = 32; off > 0; off >>= 1)
        acc += __shfl_down(acc, off, 64);
    if (lane == 0) phi_s[out] = acc + phi_b[a];
}

// Kernel B: vp[q][b][k] = sum_{a in q-th quarter} phi_s[b,a] * psi_w[a,k]
// 4-way split over the a-reduction -> 256 blocks to cut the latency-bound
// serial chain 4x. k_scores sums the 4 partials once per block (LDS-staged).
__global__ __launch_bounds__(128) void k_v(const float* __restrict__ phi_s,
                                           const float* __restrict__ psi_w,
                                           float* __restrict__ vp) {
    __shared__ float ps[DA / 4];
    const int b = blockIdx.x >> 2;
    const int q = blockIdx.x & 3;
    const int tid = threadIdx.x;
    ps[tid] = phi_s[(size_t)b * DA + q * (DA / 4) + tid];
    __syncthreads();

    const fx4* w4 = (const fx4*)psi_w;   // [a][DH/4]
    fx4 acc = {0.f, 0.f, 0.f, 0.f};
    #pragma unroll 8
    for (int a = 0; a < DA / 4; ++a) {
        const float p = ps[a];                 // LDS broadcast, conflict-free
        const fx4 w = w4[(q * (DA / 4) + a) * (DH / 4) + tid];
        acc += p * w;
    }
    ((fx4*)(vp + ((size_t)q * B + b) * DH))[tid] = acc;
}

// Kernel C (the HBM-bound pass): e[b,t] = v[b] . h[b,t];  rs[b,t] = sum_k h[b,t,k]
// 16 rows per block (all same b): q-summed v[b] staged in LDS once per block,
// each wave keeps its v fragment in registers and streams 4 rows of h with
// batched non-temporal loads (8 dwordx4 in flight).
__global__ __launch_bounds__(256) void k_scores(const float* __restrict__ h,
                                                const float* __restrict__ vp,
                                                float* __restrict__ e,
                                                float* __restrict__ rs) {
    __shared__ float vsum[DH];
    const int tid  = threadIdx.x;
    const int base = blockIdx.x * 16;          // row base; 16 | T so same b
    const int b    = base >> 11;               // /T

    // stage q-summed v[b]: 256 threads x 2 floats, 8 KB of L2 reads per block
    {
        fx2 acc = {0.f, 0.f};
        #pragma unroll
        for (int q = 0; q < 4; ++q) {
            const fx2* v2 = (const fx2*)(vp + ((size_t)q * B + b) * DH);
            acc += v2[tid];
        }
        ((fx2*)vsum)[tid] = acc;
    }
    __syncthreads();

    const int wave = tid >> 6;
    const int lane = tid & 63;
    const fx4 vA = ((const fx4*)vsum)[lane * 2];
    const fx4 vB = ((const fx4*)vsum)[lane * 2 + 1];

    const int row0 = base + wave * 4;
    fx4 hA[4], hB[4];
    #pragma unroll
    for (int r = 0; r < 4; ++r) {
        const fx4* h4 = (const fx4*)(h + (size_t)(row0 + r) * DH);
        hA[r] = __builtin_nontemporal_load(&h4[lane * 2]);
        hB[r] = __builtin_nontemporal_load(&h4[lane * 2 + 1]);
    }

    float dot[4], sum[4];
    #pragma unroll
    for (int r = 0; r < 4; ++r) {
        dot[r] = hA[r].x * vA.x + hA[r].y * vA.y + hA[r].z * vA.z + hA[r].w * vA.w
               + hB[r].x * vB.x + hB[r].y * vB.y + hB[r].z * vB.z + hB[r].w * vB.w;
        sum[r] = hA[r].x + hA[r].y + hA[r].z + hA[r].w
               + hB[r].x + hB[r].y + hB[r].z + hB[r].w;
    }
    #pragma unroll
    for (int off = 32; off > 0; off >>= 1) {
        #pragma unroll
        for (int r = 0; r < 4; ++r) {
            dot[r] += __shfl_down(dot[r], off, 64);
            sum[r] += __shfl_down(sum[r], off, 64);
        }
    }
    if (lane == 0) {
        #pragma unroll
        for (int r = 0; r < 4; ++r) { e[row0 + r] = dot[r]; rs[row0 + r] = sum[r]; }
    }
}

// Kernel D: per-b softmax over t, fused with rowsum multiply.
// Shuffle-based reductions: 3 __syncthreads total (vs 16 tree rounds).
__global__ __launch_bounds__(256) void k_softmax(const float* __restrict__ e,
                                                 const float* __restrict__ rs,
                                                 float* __restrict__ c) {
    __shared__ float wred[4];
    const int b = blockIdx.x;
    const int tid  = threadIdx.x;
    const int wave = tid >> 6;
    const int lane = tid & 63;
    const fx4* eb = (const fx4*)(e + (size_t)b * T);

    fx4 evA = eb[tid * 2], evB = eb[tid * 2 + 1];

    float m = fmaxf(fmaxf(fmaxf(evA.x, evA.y), fmaxf(evA.z, evA.w)),
                    fmaxf(fmaxf(evB.x, evB.y), fmaxf(evB.z, evB.w)));
    #pragma unroll
    for (int off = 32; off > 0; off >>= 1)
        m = fmaxf(m, __shfl_down(m, off, 64));
    if (lane == 0) wred[wave] = m;
    __syncthreads();
    m = fmaxf(fmaxf(wred[0], wred[1]), fmaxf(wred[2], wred[3]));

    evA.x = expf(evA.x - m); evA.y = expf(evA.y - m);
    evA.z = expf(evA.z - m); evA.w = expf(evA.w - m);
    evB.x = expf(evB.x - m); evB.y = expf(evB.y - m);
    evB.z = expf(evB.z - m); evB.w = expf(evB.w - m);
    float lsum = evA.x + evA.y + evA.z + evA.w + evB.x + evB.y + evB.z + evB.w;
    #pragma unroll
    for (int off = 32; off > 0; off >>= 1)
        lsum += __shfl_down(lsum, off, 64);
    __syncthreads();              // protect wred reuse
    if (lane == 0) wred[wave] = lsum;
    __syncthreads();
    const float inv = 1.0f / (wred[0] + wred[1] + wred[2] + wred[3]);

    const fx4* rb = (const fx4*)(rs + (size_t)b * T);
    fx4* cb = (fx4*)(c + (size_t)b * T);
    fx4 rA = rb[tid * 2], rB = rb[tid * 2 + 1];
    fx4 oA, oB;
    oA.x = evA.x * inv * rA.x; oA.y = evA.y * inv * rA.y;
    oA.z = evA.z * inv * rA.z; oA.w = evA.w * inv * rA.w;
    oB.x = evB.x * inv * rB.x; oB.y = evB.y * inv * rB.y;
    oB.z = evB.z * inv * rB.z; oB.w = evB.w * inv * rB.w;
    cb[tid * 2] = oA;
    cb[tid * 2 + 1] = oB;
}

extern "C" void kernel_launch(void* const* d_in, const int* in_sizes, int n_in,
                              void* d_out, int out_size, void* d_ws, size_t ws_size,
                              hipStream_t stream) {
    const float* s     = (const float*)d_in[0];
    const float* h     = (const float*)d_in[1];
    const float* phi_w = (const float*)d_in[2];
    const float* phi_b = (const float*)d_in[3];
    const float* psi_w = (const float*)d_in[4];
    // d_in[5] = psi_b: adds a per-b constant to e[b,:] -> cancels in softmax.
    (void)in_sizes; (void)n_in; (void)out_size; (void)ws_size;

    float* out = (float*)d_out;
    float* ws  = (float*)d_ws;
    float* phi_s = ws;                    // B*DA     floats (128 KB)
    float* vp    = phi_s + B * DA;        // 4*B*DH   floats (512 KB)
    float* e     = vp + 4 * B * DH;       // B*T      floats (512 KB)
    float* rs    = e + B * T;             // B*T      floats (512 KB)

    k_phi    <<<B * DA / 4, 256, 0, stream>>>(s, phi_w, phi_b, phi_s);
    k_v      <<<B * 4,      128, 0, stream>>>(phi_s, psi_w, vp);
    k_scores <<<B * T / 16, 256, 0, stream>>>(h, vp, e, rs);
    k_softmax<<<B,          256, 0, stream>>>(e, rs, out);
}